// Round 1
// baseline (3990.265 us; speedup 1.0000x reference)
//
#include <hip/hip_runtime.h>
#include <hip/hip_fp16.h>
#include <cstdint>
#include <cstddef>

// Problem constants (fixed by the reference)
#define HIDDEN 4096
#define INTER  11008
#define NTOK   4096          // B*S = 4*1024
#define NG1    (HIDDEN/64)   // 64 groups along hidden
#define NG2    (INTER/64)    // 172 groups along inter

typedef _Float16 f16;
typedef _Float16 f16x8 __attribute__((ext_vector_type(8)));
typedef float    f32x4 __attribute__((ext_vector_type(4)));

// ---- lgkm-only workgroup barrier: NO vmcnt drain (global loads stay in flight).
// asm-with-memory-clobber on both sides so LLVM cannot hoist/sink LDS ops across.
__device__ __forceinline__ void wg_barrier_lgkm() {
  asm volatile("s_waitcnt lgkmcnt(0)" ::: "memory");
  __builtin_amdgcn_s_barrier();
  asm volatile("" ::: "memory");
}

// ---- dequant one storage int32 (value in [0,256) = 2 nibbles) -> 2 f16
// w = (q - z) * s via exact f16 exponent trick + single pk_fma.
__device__ __forceinline__ uint32_t dq2(uint32_t b, __half2 s2, __half2 nzs) {
  uint32_t qb = 0x64006400u | (b >> 4) | ((b & 0xFu) << 16);
  __half2 hq = __builtin_bit_cast(__half2, qb);
  __half2 t  = __hsub2(hq, __builtin_bit_cast(__half2, 0x64006400u));
  __half2 wv = __hfma2(t, s2, nzs);
  return __builtin_bit_cast(uint32_t, wv);
}

// B packed-weights + scale/zero register set (one K-group, 2 rows)
struct Bp { uint4 w0, w1; float s0, z0, s1, z1; };

// ---------------------------------------------------------------- x: fp32->f16
__global__ __launch_bounds__(256) void cvt_x(const float* __restrict__ x,
                                             f16* __restrict__ xh) {
  size_t i = ((size_t)blockIdx.x * 256 + threadIdx.x) * 8;
  float4 a = *(const float4*)(x + i);
  float4 b = *(const float4*)(x + i + 4);
  f16x8 o = {(f16)a.x, (f16)a.y, (f16)a.z, (f16)a.w,
             (f16)b.x, (f16)b.y, (f16)b.z, (f16)b.w};
  *(f16x8*)(xh + i) = o;
}

// -------------------------------------------- GEMM1: h = silu(x Wg^T) * (x Wu^T)
// Block 256M x 64N dual, 8 waves (wave tile 64 x 32+32), BK=64 = 1 quant group.
// NEW STRUCTURE: A reg-staged into a SINGLE 32K LDS buffer; B double-buffered
// (2 x 8K per matrix). Per K-step:
//   loadA(kt+1)->regs, loadB(kt+2)->regs      (fly across barriers)
//   writeB(kt+1) -> Bbuf[(kt+1)&1]  ||  compute(kt)   (dequant overlaps MFMA)
//   barrier(a, lgkm-only)  -> writeA(regs->Abuf) -> barrier(b, lgkm-only)
// No vmcnt(0) drain anywhere: all VMEM waits are compiler-precise register uses.
// LDS = 32K (A) + 16K (Bg dbuf) + 16K (Bu dbuf) = 64 KB -> 2 blocks/CU.
__global__ __launch_bounds__(512, 4) void gemm_gateup(
    const f16* __restrict__ xh,
    const uint32_t* __restrict__ gq, const uint32_t* __restrict__ uq,
    const float* __restrict__ gs, const float* __restrict__ gz,
    const float* __restrict__ us, const float* __restrict__ uz,
    f16* __restrict__ h) {
  extern __shared__ char smem[];
  f16* lA = (f16*)smem;                  // 32 KB single buffer
  char* lBgBase = smem + 32768;          // 2 x 8 KB
  char* lBuBase = smem + 49152;          // 2 x 8 KB
  const int tid = threadIdx.x, lane = tid & 63, wave = tid >> 6;
  const int bm = blockIdx.x, bn = blockIdx.y;      // bm<16, bn<172
  const int wm = wave >> 1, wn = wave & 1;

  // ---- A staging addressing: 4 chunks/thread, rows i*64 + (tid>>3)
  const int arow0 = tid >> 3;
  const int ak8s  = (tid & 7) ^ (arow0 & 7);       // pre-swizzled global source
  const f16* aptr = xh + (size_t)(bm * 256 + arow0) * HIDDEN + ak8s * 8;
  const int aoff = tid * 16;             // + i*8192 per chunk (linear LDS dest)

  // ---- B staging addressing: 2 rows/thread of one matrix
  const int mat = tid >> 8;              // 0 = gate, 1 = up (wave-uniform)
  const int t = tid & 255;
  const int brow0 = t >> 3;
  const uint32_t* qp = (mat ? uq : gq) + (size_t)(bn * 64 + brow0) * (HIDDEN / 2) + (t & 7) * 4;
  const float* sp = (mat ? us : gs) + (size_t)(bn * 64 + brow0) * NG1;
  const float* zp = (mat ? uz : gz) + (size_t)(bn * 64 + brow0) * NG1;
  char* lbBase = mat ? lBuBase : lBgBase;
  const int bws0 = brow0 * 128 + (((t & 7) ^ (brow0 & 7)) << 4);

  // ---- fragment-read addressing
  int abase[4], asel[4];
#pragma unroll
  for (int im = 0; im < 4; ++im) {
    int r = wm * 64 + im * 16 + (lane & 15);
    abase[im] = r * 128; asel[im] = r & 7;
  }
  int bbase[2], bsel[2];
#pragma unroll
  for (int in_ = 0; in_ < 2; ++in_) {
    int r = wn * 32 + in_ * 16 + (lane & 15);
    bbase[in_] = r * 128; bsel[in_] = r & 7;
  }
  const int kchunk = lane >> 4;

  f32x4 accg[4][2] = {};
  f32x4 accu[4][2] = {};

  uint4 ar[4];                           // A stage registers (64 B/thread)
  auto loadA = [&](int kt) {
#pragma unroll
    for (int i = 0; i < 4; ++i)
      ar[i] = *(const uint4*)(aptr + (size_t)kt * 64 + (size_t)i * 64 * HIDDEN);
  };
  auto writeA = [&]() {
#pragma unroll
    for (int i = 0; i < 4; ++i)
      *(uint4*)((char*)lA + aoff + i * 8192) = ar[i];
  };
  auto loadB = [&](int ktn, Bp& r) {
    r.w0 = *(const uint4*)(qp + (size_t)ktn * 32);
    r.w1 = *(const uint4*)(qp + (size_t)32 * (HIDDEN / 2) + (size_t)ktn * 32);
    r.s0 = sp[ktn]; r.z0 = zp[ktn];
    r.s1 = sp[32 * NG1 + ktn]; r.z1 = zp[32 * NG1 + ktn];
  };
  auto writeB = [&](const Bp& r, int pb) {
    char* lb = lbBase + pb * 8192;
    __half2 s0 = __float2half2_rn(r.s0), n0 = __float2half2_rn(-r.z0 * r.s0);
    __half2 s1 = __float2half2_rn(r.s1), n1 = __float2half2_rn(-r.z1 * r.s1);
    uint4 o0, o1;
    o0.x = dq2(r.w0.x, s0, n0); o0.y = dq2(r.w0.y, s0, n0);
    o0.z = dq2(r.w0.z, s0, n0); o0.w = dq2(r.w0.w, s0, n0);
    o1.x = dq2(r.w1.x, s1, n1); o1.y = dq2(r.w1.y, s1, n1);
    o1.z = dq2(r.w1.z, s1, n1); o1.w = dq2(r.w1.w, s1, n1);
    *(uint4*)(lb + bws0) = o0;
    *(uint4*)(lb + bws0 + 32 * 128) = o1;
  };
  auto compute = [&](int cb) {
    const char* bg0 = lBgBase + cb * 8192;
    const char* bu0 = lBuBase + cb * 8192;
#pragma unroll
    for (int ks = 0; ks < 2; ++ks) {
      int kc = ks * 4 + kchunk;
      f16x8 a[4], bg[2], bu[2];
#pragma unroll
      for (int im = 0; im < 4; ++im)
        a[im] = *(const f16x8*)((const char*)lA + abase[im] + ((kc ^ asel[im]) << 4));
#pragma unroll
      for (int in_ = 0; in_ < 2; ++in_) {
        bg[in_] = *(const f16x8*)(bg0 + bbase[in_] + ((kc ^ bsel[in_]) << 4));
        bu[in_] = *(const f16x8*)(bu0 + bbase[in_] + ((kc ^ bsel[in_]) << 4));
      }
      __builtin_amdgcn_s_setprio(1);
#pragma unroll
      for (int im = 0; im < 4; ++im)
#pragma unroll
        for (int in_ = 0; in_ < 2; ++in_) {
          accg[im][in_] = __builtin_amdgcn_mfma_f32_16x16x32_f16(a[im], bg[in_], accg[im][in_], 0, 0, 0);
          accu[im][in_] = __builtin_amdgcn_mfma_f32_16x16x32_f16(a[im], bu[in_], accu[im][in_], 0, 0, 0);
        }
      __builtin_amdgcn_s_setprio(0);
    }
  };

  // ---- prologue: tile 0 staged (latency exposed once); B(1) loads left in flight
  loadA(0);
  Bp br0, brc, brn;
  loadB(0, br0);
  loadB(1, brc);
  writeA();
  writeB(br0, 0);
  wg_barrier_lgkm();

  // ---- pipelined main loop (no vmcnt drains; two lgkm-only barriers)
  for (int kt = 0; kt < NG1 - 1; ++kt) {
    loadA(kt + 1);                                         // A(kt+1) -> regs
    loadB(kt + 2 < NG1 ? kt + 2 : NG1 - 1, brn);           // B(kt+2) -> regs
    __builtin_amdgcn_sched_barrier(0);                     // pin loads at region top
    writeB(brc, (kt + 1) & 1);          // dequant B(kt+1) -> other buf (overlaps MFMA)
    compute(kt & 1);                                       // tile kt
    wg_barrier_lgkm();                  // (a) all reads of lA/Bbuf done
    writeA();                           // A(kt+1) regs -> lA
    wg_barrier_lgkm();                  // (b) lA ready
    brc = brn;
  }
  compute((NG1 - 1) & 1);

  // ---- epilogue: h = silu(g)*u, f16.  C/D: col=lane&15, row=(lane>>4)*4+r
#pragma unroll
  for (int im = 0; im < 4; ++im)
#pragma unroll
    for (int in_ = 0; in_ < 2; ++in_)
#pragma unroll
      for (int r = 0; r < 4; ++r) {
        int row = bm * 256 + wm * 64 + im * 16 + (lane >> 4) * 4 + r;
        int col = bn * 64 + wn * 32 + in_ * 16 + (lane & 15);
        float g = accg[im][in_][r];
        float u = accu[im][in_][r];
        float hv = (g / (1.0f + __expf(-g))) * u;
        h[(size_t)row * INTER + col] = (f16)hv;
      }
}

// -------------------------------------------- GEMM2: out = h Wd^T  (fp32 out)
// Block 256x128, 8 waves (wave tile 64x64), same new pipelined structure.
// LDS = 32K (A single) + 2 x 16K (B dbuf) = 64 KB -> 2 blocks/CU.
__global__ __launch_bounds__(512, 4) void gemm_down(
    const f16* __restrict__ h, const uint32_t* __restrict__ dq_,
    const float* __restrict__ dsc, const float* __restrict__ dz,
    float* __restrict__ out) {
  extern __shared__ char smem[];
  f16* lA = (f16*)smem;                  // 32 KB single buffer
  char* lBBase = smem + 32768;           // 2 x 16 KB
  const int tid = threadIdx.x, lane = tid & 63, wave = tid >> 6;
  const int bm = blockIdx.x, bn = blockIdx.y;  // 16 x 32
  const int wm = wave >> 1, wn = wave & 1;

  const int arow0 = tid >> 3;
  const int ak8s  = (tid & 7) ^ (arow0 & 7);
  const f16* aptr = h + (size_t)(bm * 256 + arow0) * INTER + ak8s * 8;
  const int aoff = tid * 16;

  const int brow0 = tid >> 3;                       // 0..63, rows brow0 & brow0+64
  const uint32_t* qp = dq_ + (size_t)(bn * 128 + brow0) * (INTER / 2) + (tid & 7) * 4;
  const float* sp = dsc + (size_t)(bn * 128 + brow0) * NG2;
  const float* zp = dz + (size_t)(bn * 128 + brow0) * NG2;
  const int bws0 = brow0 * 128 + (((tid & 7) ^ (brow0 & 7)) << 4);

  int abase[4], asel[4];
#pragma unroll
  for (int im = 0; im < 4; ++im) {
    int r = wm * 64 + im * 16 + (lane & 15);
    abase[im] = r * 128; asel[im] = r & 7;
  }
  int bbase[4], bsel[4];
#pragma unroll
  for (int in_ = 0; in_ < 4; ++in_) {
    int r = wn * 64 + in_ * 16 + (lane & 15);
    bbase[in_] = r * 128; bsel[in_] = r & 7;
  }
  const int kchunk = lane >> 4;

  f32x4 acc[4][4] = {};

  uint4 ar[4];
  auto loadA = [&](int kt) {
#pragma unroll
    for (int i = 0; i < 4; ++i)
      ar[i] = *(const uint4*)(aptr + (size_t)kt * 64 + (size_t)i * 64 * INTER);
  };
  auto writeA = [&]() {
#pragma unroll
    for (int i = 0; i < 4; ++i)
      *(uint4*)((char*)lA + aoff + i * 8192) = ar[i];
  };
  auto loadB = [&](int ktn, Bp& r) {
    r.w0 = *(const uint4*)(qp + (size_t)ktn * 32);
    r.w1 = *(const uint4*)(qp + (size_t)64 * (INTER / 2) + (size_t)ktn * 32);
    r.s0 = sp[ktn]; r.z0 = zp[ktn];
    r.s1 = sp[64 * NG2 + ktn]; r.z1 = zp[64 * NG2 + ktn];
  };
  auto writeB = [&](const Bp& r, int pb) {
    char* lb = lBBase + pb * 16384;
    __half2 s0 = __float2half2_rn(r.s0), n0 = __float2half2_rn(-r.z0 * r.s0);
    __half2 s1 = __float2half2_rn(r.s1), n1 = __float2half2_rn(-r.z1 * r.s1);
    uint4 o0, o1;
    o0.x = dq2(r.w0.x, s0, n0); o0.y = dq2(r.w0.y, s0, n0);
    o0.z = dq2(r.w0.z, s0, n0); o0.w = dq2(r.w0.w, s0, n0);
    o1.x = dq2(r.w1.x, s1, n1); o1.y = dq2(r.w1.y, s1, n1);
    o1.z = dq2(r.w1.z, s1, n1); o1.w = dq2(r.w1.w, s1, n1);
    *(uint4*)(lb + bws0) = o0;
    *(uint4*)(lb + bws0 + 64 * 128) = o1;
  };
  auto compute = [&](int cb) {
    const char* lb0 = lBBase + cb * 16384;
#pragma unroll
    for (int ks = 0; ks < 2; ++ks) {
      int kc = ks * 4 + kchunk;
      f16x8 a[4], b[4];
#pragma unroll
      for (int im = 0; im < 4; ++im)
        a[im] = *(const f16x8*)((const char*)lA + abase[im] + ((kc ^ asel[im]) << 4));
#pragma unroll
      for (int in_ = 0; in_ < 4; ++in_)
        b[in_] = *(const f16x8*)(lb0 + bbase[in_] + ((kc ^ bsel[in_]) << 4));
      __builtin_amdgcn_s_setprio(1);
#pragma unroll
      for (int im = 0; im < 4; ++im)
#pragma unroll
        for (int in_ = 0; in_ < 4; ++in_)
          acc[im][in_] = __builtin_amdgcn_mfma_f32_16x16x32_f16(a[im], b[in_], acc[im][in_], 0, 0, 0);
      __builtin_amdgcn_s_setprio(0);
    }
  };

  loadA(0);
  Bp br0, brc, brn;
  loadB(0, br0);
  loadB(1, brc);
  writeA();
  writeB(br0, 0);
  wg_barrier_lgkm();

  for (int kt = 0; kt < NG2 - 1; ++kt) {
    loadA(kt + 1);
    loadB(kt + 2 < NG2 ? kt + 2 : NG2 - 1, brn);
    __builtin_amdgcn_sched_barrier(0);
    writeB(brc, (kt + 1) & 1);
    compute(kt & 1);
    wg_barrier_lgkm();
    writeA();
    wg_barrier_lgkm();
    brc = brn;
  }
  compute((NG2 - 1) & 1);

#pragma unroll
  for (int im = 0; im < 4; ++im)
#pragma unroll
    for (int in_ = 0; in_ < 4; ++in_)
#pragma unroll
      for (int r = 0; r < 4; ++r) {
        int row = bm * 256 + wm * 64 + im * 16 + (lane >> 4) * 4 + r;
        int col = bn * 128 + wn * 64 + in_ * 16 + (lane & 15);
        out[(size_t)row * HIDDEN + col] = acc[im][in_][r];
      }
}

// ------------------------------------------------------------------- launcher
extern "C" void kernel_launch(void* const* d_in, const int* in_sizes, int n_in,
                              void* d_out, int out_size, void* d_ws, size_t ws_size,
                              hipStream_t stream) {
  const float*    x   = (const float*)d_in[0];
  const uint32_t* gq  = (const uint32_t*)d_in[1];
  const uint32_t* uq  = (const uint32_t*)d_in[2];
  const uint32_t* dqw = (const uint32_t*)d_in[3];
  const float*    gs  = (const float*)d_in[4];
  const float*    gz  = (const float*)d_in[5];
  const float*    us  = (const float*)d_in[6];
  const float*    uz  = (const float*)d_in[7];
  const float*    dsc = (const float*)d_in[8];
  const float*    dzz = (const float*)d_in[9];

  f16* xh   = (f16*)d_ws;                                        // 32 MB
  f16* hbuf = (f16*)((char*)d_ws + (size_t)NTOK * HIDDEN * 2);   // 90 MB
  float* out = (float*)d_out;

  const int LDS_BYTES = 64 * 1024;
  (void)hipFuncSetAttribute((const void*)gemm_gateup,
                            hipFuncAttributeMaxDynamicSharedMemorySize, LDS_BYTES);
  (void)hipFuncSetAttribute((const void*)gemm_down,
                            hipFuncAttributeMaxDynamicSharedMemorySize, LDS_BYTES);

  cvt_x<<<dim3((NTOK * HIDDEN) / (256 * 8)), 256, 0, stream>>>(x, xh);
  gemm_gateup<<<dim3(NTOK / 256, INTER / 64), 512, LDS_BYTES, stream>>>(
      xh, gq, uq, gs, gz, us, uz, hbuf);
  gemm_down<<<dim3(NTOK / 256, HIDDEN / 128), 512, LDS_BYTES, stream>>>(
      hbuf, dqw, dsc, dzz, out);
}

// Round 2
// 2152.474 us; speedup vs baseline: 1.8538x; 1.8538x over previous
//
#include <hip/hip_runtime.h>
#include <hip/hip_fp16.h>
#include <cstdint>
#include <cstddef>

// Problem constants (fixed by the reference)
#define HIDDEN 4096
#define INTER  11008
#define NTOK   4096          // B*S = 4*1024
#define NG1    (HIDDEN/64)   // 64 groups along hidden
#define NG2    (INTER/64)    // 172 groups along inter

typedef _Float16 f16;
typedef _Float16 f16x8 __attribute__((ext_vector_type(8)));
typedef float    f32x4 __attribute__((ext_vector_type(4)));

// ---- async global->LDS, 16B per lane (dest must be wave-uniform base + lane*16)
__device__ __forceinline__ void g2lds16(const void* g, void* l) {
  __builtin_amdgcn_global_load_lds(
      (const __attribute__((address_space(1))) uint32_t*)g,
      (__attribute__((address_space(3))) uint32_t*)l, 16, 0, 0);
}

// ---- counted-vmcnt barrier: waits lgkm fully, but leaves the 6 newest VMEM
// ops (the B prefetch) in flight. The 4 A-DMAs are older than the B prefetch
// (pinned by sched_barrier), so vmcnt(6) completes them in EVERY wave before
// any wave crosses -> cross-wave LDS-A readiness without a vmcnt(0) drain.
__device__ __forceinline__ void wg_barrier_v6() {
  asm volatile("s_waitcnt vmcnt(6) lgkmcnt(0)" ::: "memory");
  __builtin_amdgcn_s_barrier();
  asm volatile("" ::: "memory");
}

// ---- dequant one storage int32 (value in [0,256) = 2 nibbles) -> 2 f16
// w = (q - z) * s via exact f16 exponent trick + single pk_fma.
__device__ __forceinline__ uint32_t dq2(uint32_t b, __half2 s2, __half2 nzs) {
  uint32_t qb = 0x64006400u | (b >> 4) | ((b & 0xFu) << 16);
  __half2 hq = __builtin_bit_cast(__half2, qb);
  __half2 t  = __hsub2(hq, __builtin_bit_cast(__half2, 0x64006400u));
  __half2 wv = __hfma2(t, s2, nzs);
  return __builtin_bit_cast(uint32_t, wv);
}

// B packed-weights + scale/zero register set (one K-group, 2 rows)
struct Bp { uint4 w0, w1; float s0, z0, s1, z1; };

// ---------------------------------------------------------------- x: fp32->f16
__global__ __launch_bounds__(256) void cvt_x(const float* __restrict__ x,
                                             f16* __restrict__ xh) {
  size_t i = ((size_t)blockIdx.x * 256 + threadIdx.x) * 8;
  float4 a = *(const float4*)(x + i);
  float4 b = *(const float4*)(x + i + 4);
  f16x8 o = {(f16)a.x, (f16)a.y, (f16)a.z, (f16)a.w,
             (f16)b.x, (f16)b.y, (f16)b.z, (f16)b.w};
  *(f16x8*)(xh + i) = o;
}

// -------------------------------------------- GEMM1: h = silu(x Wg^T) * (x Wu^T)
// Block 256M x 64N dual, 8 waves (wave tile 64 x 32+32), BK=64 = 1 quant group.
// A: global_load_lds DMA (zero VGPR cost), double-buffered 2x32K.
// B: double-buffered 2x(8K+8K); dequant of tile kt+1 runs in the SAME region
// as compute(kt) -> VALU dequant overlaps MFMA across waves.
// ONE barrier per K-step, counted vmcnt(6) (B prefetch stays in flight).
// LDS = 96 KB -> 1 block/CU, 8 waves. launch_bounds(512,2): VGPR cap 256,
// no spills (round-1 lesson: spills showed as 5.5 GB WRITE_SIZE).
__global__ __launch_bounds__(512, 2) void gemm_gateup(
    const f16* __restrict__ xh,
    const uint32_t* __restrict__ gq, const uint32_t* __restrict__ uq,
    const float* __restrict__ gs, const float* __restrict__ gz,
    const float* __restrict__ us, const float* __restrict__ uz,
    f16* __restrict__ h) {
  extern __shared__ char smem[];
  f16* lA0 = (f16*)smem;                 // 32 KB
  f16* lA1 = (f16*)(smem + 32768);       // 32 KB
  char* lBg = smem + 65536;              // 2 x 8 KB  (+ pb*8192)
  char* lBu = smem + 81920;              // 2 x 8 KB  (+ pb*8192)
  const int tid = threadIdx.x, lane = tid & 63, wave = tid >> 6;
  const int bm = blockIdx.x, bn = blockIdx.y;      // bm<16, bn<172
  const int wm = wave >> 1, wn = wave & 1;

  // ---- A staging addressing: 4 chunks/thread, rows i*64 + (tid>>3)
  const int arow0 = tid >> 3;
  const int ak8s  = (tid & 7) ^ (arow0 & 7);       // pre-swizzled global source
  const f16* aptr = xh + (size_t)(bm * 256 + arow0) * HIDDEN + ak8s * 8;
  const int aoff = tid * 16;             // + i*8192 per chunk (linear LDS dest)

  // ---- B staging addressing: 2 rows/thread of one matrix
  const int mat = tid >> 8;              // 0 = gate, 1 = up (wave-uniform)
  const int t = tid & 255;
  const int brow0 = t >> 3;
  const uint32_t* qp = (mat ? uq : gq) + (size_t)(bn * 64 + brow0) * (HIDDEN / 2) + (t & 7) * 4;
  const float* sp = (mat ? us : gs) + (size_t)(bn * 64 + brow0) * NG1;
  const float* zp = (mat ? uz : gz) + (size_t)(bn * 64 + brow0) * NG1;
  char* lbBase = mat ? lBu : lBg;
  const int bws0 = brow0 * 128 + (((t & 7) ^ (brow0 & 7)) << 4);

  // ---- fragment-read addressing
  int abase[4], asel[4];
#pragma unroll
  for (int im = 0; im < 4; ++im) {
    int r = wm * 64 + im * 16 + (lane & 15);
    abase[im] = r * 128; asel[im] = r & 7;
  }
  int bbase[2], bsel[2];
#pragma unroll
  for (int in_ = 0; in_ < 2; ++in_) {
    int r = wn * 32 + in_ * 16 + (lane & 15);
    bbase[in_] = r * 128; bsel[in_] = r & 7;
  }
  const int kchunk = lane >> 4;

  f32x4 accg[4][2] = {};
  f32x4 accu[4][2] = {};

  auto stageA = [&](const f16* src, f16* dst) {
#pragma unroll
    for (int i = 0; i < 4; ++i)
      g2lds16(src + (size_t)i * 64 * HIDDEN, (char*)dst + aoff + i * 8192);
  };
  auto loadB = [&](int ktn, Bp& r) {
    r.w0 = *(const uint4*)(qp + (size_t)ktn * 32);
    r.w1 = *(const uint4*)(qp + (size_t)32 * (HIDDEN / 2) + (size_t)ktn * 32);
    r.s0 = sp[ktn]; r.z0 = zp[ktn];
    r.s1 = sp[32 * NG1 + ktn]; r.z1 = zp[32 * NG1 + ktn];
  };
  auto writeB = [&](const Bp& r, int pb) {
    char* lb = lbBase + pb * 8192;
    __half2 s0 = __float2half2_rn(r.s0), n0 = __float2half2_rn(-r.z0 * r.s0);
    __half2 s1 = __float2half2_rn(r.s1), n1 = __float2half2_rn(-r.z1 * r.s1);
    uint4 o0, o1;
    o0.x = dq2(r.w0.x, s0, n0); o0.y = dq2(r.w0.y, s0, n0);
    o0.z = dq2(r.w0.z, s0, n0); o0.w = dq2(r.w0.w, s0, n0);
    o1.x = dq2(r.w1.x, s1, n1); o1.y = dq2(r.w1.y, s1, n1);
    o1.z = dq2(r.w1.z, s1, n1); o1.w = dq2(r.w1.w, s1, n1);
    *(uint4*)(lb + bws0) = o0;
    *(uint4*)(lb + bws0 + 32 * 128) = o1;
  };
  auto compute = [&](const f16* lA, int cb) {
    const char* bg0 = lBg + cb * 8192;
    const char* bu0 = lBu + cb * 8192;
#pragma unroll
    for (int ks = 0; ks < 2; ++ks) {
      int kc = ks * 4 + kchunk;
      f16x8 a[4], bg[2], bu[2];
#pragma unroll
      for (int im = 0; im < 4; ++im)
        a[im] = *(const f16x8*)((const char*)lA + abase[im] + ((kc ^ asel[im]) << 4));
#pragma unroll
      for (int in_ = 0; in_ < 2; ++in_) {
        bg[in_] = *(const f16x8*)(bg0 + bbase[in_] + ((kc ^ bsel[in_]) << 4));
        bu[in_] = *(const f16x8*)(bu0 + bbase[in_] + ((kc ^ bsel[in_]) << 4));
      }
      __builtin_amdgcn_s_setprio(1);
#pragma unroll
      for (int im = 0; im < 4; ++im)
#pragma unroll
        for (int in_ = 0; in_ < 2; ++in_) {
          accg[im][in_] = __builtin_amdgcn_mfma_f32_16x16x32_f16(a[im], bg[in_], accg[im][in_], 0, 0, 0);
          accu[im][in_] = __builtin_amdgcn_mfma_f32_16x16x32_f16(a[im], bu[in_], accu[im][in_], 0, 0, 0);
        }
      __builtin_amdgcn_s_setprio(0);
    }
  };

  // ---- prologue: tile 0 staged; B(1) prefetch left in flight across barrier
  stageA(aptr, lA0);
  __builtin_amdgcn_sched_barrier(0);
  Bp brc;
  {
    Bp br0;
    loadB(0, br0);
    writeB(br0, 0);      // implicit full wait (once)
  }
  loadB(1, brc);
  wg_barrier_v6();

  // ---- main loop: ONE counted barrier per K-step
  for (int kt = 0; kt < NG1 - 1; ++kt) {
    stageA(aptr + (size_t)(kt + 1) * 64, (kt & 1) ? lA0 : lA1);  // 4 DMA (oldest)
    __builtin_amdgcn_sched_barrier(0);                           // pin DMA first
    writeB(brc, (kt + 1) & 1);         // dequant B(kt+1): overlaps MFMA cross-wave
    loadB(kt + 2 < NG1 ? kt + 2 : NG1 - 1, brc);                 // 6 VMEM (newest)
    compute((kt & 1) ? lA1 : lA0, kt & 1);                       // tile kt
    wg_barrier_v6();                   // drains DMAs, keeps B prefetch flying
  }
  compute(((NG1 - 1) & 1) ? lA1 : lA0, (NG1 - 1) & 1);

  // ---- epilogue: h = silu(g)*u, f16.  C/D: col=lane&15, row=(lane>>4)*4+r
#pragma unroll
  for (int im = 0; im < 4; ++im)
#pragma unroll
    for (int in_ = 0; in_ < 2; ++in_)
#pragma unroll
      for (int r = 0; r < 4; ++r) {
        int row = bm * 256 + wm * 64 + im * 16 + (lane >> 4) * 4 + r;
        int col = bn * 64 + wn * 32 + in_ * 16 + (lane & 15);
        float g = accg[im][in_][r];
        float u = accu[im][in_][r];
        float hv = (g / (1.0f + __expf(-g))) * u;
        h[(size_t)row * INTER + col] = (f16)hv;
      }
}

// -------------------------------------------- GEMM2: out = h Wd^T  (fp32 out)
// Block 256x128, 8 waves (wave tile 64x64), same single-counted-barrier structure.
// LDS = 2x32K (A dbuf, DMA) + 2x16K (B dbuf) = 96 KB -> 1 block/CU.
__global__ __launch_bounds__(512, 2) void gemm_down(
    const f16* __restrict__ h, const uint32_t* __restrict__ dq_,
    const float* __restrict__ dsc, const float* __restrict__ dz,
    float* __restrict__ out) {
  extern __shared__ char smem[];
  f16* lA0 = (f16*)smem;
  f16* lA1 = (f16*)(smem + 32768);
  char* lB = smem + 65536;               // 2 x 16 KB (+ pb*16384)
  const int tid = threadIdx.x, lane = tid & 63, wave = tid >> 6;
  const int bm = blockIdx.x, bn = blockIdx.y;  // 16 x 32
  const int wm = wave >> 1, wn = wave & 1;

  const int arow0 = tid >> 3;
  const int ak8s  = (tid & 7) ^ (arow0 & 7);
  const f16* aptr = h + (size_t)(bm * 256 + arow0) * INTER + ak8s * 8;
  const int aoff = tid * 16;

  const int brow0 = tid >> 3;                       // 0..63, rows brow0 & brow0+64
  const uint32_t* qp = dq_ + (size_t)(bn * 128 + brow0) * (INTER / 2) + (tid & 7) * 4;
  const float* sp = dsc + (size_t)(bn * 128 + brow0) * NG2;
  const float* zp = dz + (size_t)(bn * 128 + brow0) * NG2;
  const int bws0 = brow0 * 128 + (((tid & 7) ^ (brow0 & 7)) << 4);

  int abase[4], asel[4];
#pragma unroll
  for (int im = 0; im < 4; ++im) {
    int r = wm * 64 + im * 16 + (lane & 15);
    abase[im] = r * 128; asel[im] = r & 7;
  }
  int bbase[4], bsel[4];
#pragma unroll
  for (int in_ = 0; in_ < 4; ++in_) {
    int r = wn * 64 + in_ * 16 + (lane & 15);
    bbase[in_] = r * 128; bsel[in_] = r & 7;
  }
  const int kchunk = lane >> 4;

  f32x4 acc[4][4] = {};

  auto stageA = [&](const f16* src, f16* dst) {
#pragma unroll
    for (int i = 0; i < 4; ++i)
      g2lds16(src + (size_t)i * 64 * INTER, (char*)dst + aoff + i * 8192);
  };
  auto loadB = [&](int ktn, Bp& r) {
    r.w0 = *(const uint4*)(qp + (size_t)ktn * 32);
    r.w1 = *(const uint4*)(qp + (size_t)64 * (INTER / 2) + (size_t)ktn * 32);
    r.s0 = sp[ktn]; r.z0 = zp[ktn];
    r.s1 = sp[64 * NG2 + ktn]; r.z1 = zp[64 * NG2 + ktn];
  };
  auto writeB = [&](const Bp& r, int pb) {
    char* lb = lB + pb * 16384;
    __half2 s0 = __float2half2_rn(r.s0), n0 = __float2half2_rn(-r.z0 * r.s0);
    __half2 s1 = __float2half2_rn(r.s1), n1 = __float2half2_rn(-r.z1 * r.s1);
    uint4 o0, o1;
    o0.x = dq2(r.w0.x, s0, n0); o0.y = dq2(r.w0.y, s0, n0);
    o0.z = dq2(r.w0.z, s0, n0); o0.w = dq2(r.w0.w, s0, n0);
    o1.x = dq2(r.w1.x, s1, n1); o1.y = dq2(r.w1.y, s1, n1);
    o1.z = dq2(r.w1.z, s1, n1); o1.w = dq2(r.w1.w, s1, n1);
    *(uint4*)(lb + bws0) = o0;
    *(uint4*)(lb + bws0 + 64 * 128) = o1;
  };
  auto compute = [&](const f16* lA, int cb) {
    const char* lb0 = lB + cb * 16384;
#pragma unroll
    for (int ks = 0; ks < 2; ++ks) {
      int kc = ks * 4 + kchunk;
      f16x8 a[4], b[4];
#pragma unroll
      for (int im = 0; im < 4; ++im)
        a[im] = *(const f16x8*)((const char*)lA + abase[im] + ((kc ^ asel[im]) << 4));
#pragma unroll
      for (int in_ = 0; in_ < 4; ++in_)
        b[in_] = *(const f16x8*)(lb0 + bbase[in_] + ((kc ^ bsel[in_]) << 4));
      __builtin_amdgcn_s_setprio(1);
#pragma unroll
      for (int im = 0; im < 4; ++im)
#pragma unroll
        for (int in_ = 0; in_ < 4; ++in_)
          acc[im][in_] = __builtin_amdgcn_mfma_f32_16x16x32_f16(a[im], b[in_], acc[im][in_], 0, 0, 0);
      __builtin_amdgcn_s_setprio(0);
    }
  };

  stageA(aptr, lA0);
  __builtin_amdgcn_sched_barrier(0);
  Bp brc;
  {
    Bp br0;
    loadB(0, br0);
    writeB(br0, 0);
  }
  loadB(1, brc);
  wg_barrier_v6();

  for (int kt = 0; kt < NG2 - 1; ++kt) {
    stageA(aptr + (size_t)(kt + 1) * 64, (kt & 1) ? lA0 : lA1);
    __builtin_amdgcn_sched_barrier(0);
    writeB(brc, (kt + 1) & 1);
    loadB(kt + 2 < NG2 ? kt + 2 : NG2 - 1, brc);
    compute((kt & 1) ? lA1 : lA0, kt & 1);
    wg_barrier_v6();
  }
  compute(((NG2 - 1) & 1) ? lA1 : lA0, (NG2 - 1) & 1);

#pragma unroll
  for (int im = 0; im < 4; ++im)
#pragma unroll
    for (int in_ = 0; in_ < 4; ++in_)
#pragma unroll
      for (int r = 0; r < 4; ++r) {
        int row = bm * 256 + wm * 64 + im * 16 + (lane >> 4) * 4 + r;
        int col = bn * 128 + wn * 64 + in_ * 16 + (lane & 15);
        out[(size_t)row * HIDDEN + col] = acc[im][in_][r];
      }
}

// ------------------------------------------------------------------- launcher
extern "C" void kernel_launch(void* const* d_in, const int* in_sizes, int n_in,
                              void* d_out, int out_size, void* d_ws, size_t ws_size,
                              hipStream_t stream) {
  const float*    x   = (const float*)d_in[0];
  const uint32_t* gq  = (const uint32_t*)d_in[1];
  const uint32_t* uq  = (const uint32_t*)d_in[2];
  const uint32_t* dqw = (const uint32_t*)d_in[3];
  const float*    gs  = (const float*)d_in[4];
  const float*    gz  = (const float*)d_in[5];
  const float*    us  = (const float*)d_in[6];
  const float*    uz  = (const float*)d_in[7];
  const float*    dsc = (const float*)d_in[8];
  const float*    dzz = (const float*)d_in[9];

  f16* xh   = (f16*)d_ws;                                        // 32 MB
  f16* hbuf = (f16*)((char*)d_ws + (size_t)NTOK * HIDDEN * 2);   // 90 MB
  float* out = (float*)d_out;

  const int LDS_BYTES = 96 * 1024;
  (void)hipFuncSetAttribute((const void*)gemm_gateup,
                            hipFuncAttributeMaxDynamicSharedMemorySize, LDS_BYTES);
  (void)hipFuncSetAttribute((const void*)gemm_down,
                            hipFuncAttributeMaxDynamicSharedMemorySize, LDS_BYTES);

  cvt_x<<<dim3((NTOK * HIDDEN) / (256 * 8)), 256, 0, stream>>>(x, xh);
  gemm_gateup<<<dim3(NTOK / 256, INTER / 64), 512, LDS_BYTES, stream>>>(
      xh, gq, uq, gs, gz, us, uz, hbuf);
  gemm_down<<<dim3(NTOK / 256, HIDDEN / 128), 512, LDS_BYTES, stream>>>(
      hbuf, dqw, dsc, dzz, out);
}

// Round 4
// 1536.463 us; speedup vs baseline: 2.5970x; 1.4009x over previous
//
#include <hip/hip_runtime.h>
#include <hip/hip_fp16.h>
#include <cstdint>
#include <cstddef>

// Problem constants (fixed by the reference)
#define HIDDEN 4096
#define INTER  11008
#define NTOK   4096          // B*S = 4*1024
#define NG1    (HIDDEN/64)   // 64 groups along hidden
#define NG2    (INTER/64)    // 172 groups along inter

typedef _Float16 f16;
typedef _Float16 f16x8 __attribute__((ext_vector_type(8)));
typedef float    f32x4 __attribute__((ext_vector_type(4)));

// ---- async global->LDS, 16B per lane (dest must be wave-uniform base + lane*16)
__device__ __forceinline__ void g2lds16(const void* g, void* l) {
  __builtin_amdgcn_global_load_lds(
      (const __attribute__((address_space(1))) uint32_t*)g,
      (__attribute__((address_space(3))) uint32_t*)l, 16, 0, 0);
}

// ---- dequant one storage int32 (value in [0,256) = 2 nibbles) -> 2 f16
// w = (q - z) * s via exact f16 exponent trick + single pk_fma.
__device__ __forceinline__ uint32_t dq2(uint32_t b, __half2 s2, __half2 nzs) {
  uint32_t qb = 0x64006400u | (b >> 4) | ((b & 0xFu) << 16);
  __half2 hq = __builtin_bit_cast(__half2, qb);
  __half2 t  = __hsub2(hq, __builtin_bit_cast(__half2, 0x64006400u));
  __half2 wv = __hfma2(t, s2, nzs);
  return __builtin_bit_cast(uint32_t, wv);
}

// ---------------------------------------------------------------- x: fp32->f16
__global__ __launch_bounds__(256) void cvt_x(const float* __restrict__ x,
                                             f16* __restrict__ xh) {
  size_t i = ((size_t)blockIdx.x * 256 + threadIdx.x) * 8;
  float4 a = *(const float4*)(x + i);
  float4 b = *(const float4*)(x + i + 4);
  f16x8 o = {(f16)a.x, (f16)a.y, (f16)a.z, (f16)a.w,
             (f16)b.x, (f16)b.y, (f16)b.z, (f16)b.w};
  *(f16x8*)(xh + i) = o;
}

// ---------------------------------------------- weight dequant pass (once)
// One thread = one quant group (64 weights = 32 packed int32). Memory-bound.
__global__ __launch_bounds__(256) void deq_w(const uint32_t* __restrict__ q,
                                             const float* __restrict__ s,
                                             const float* __restrict__ z,
                                             f16* __restrict__ out) {
  int g = blockIdx.x * 256 + threadIdx.x;
  const uint32_t* qp = q + (size_t)g * 32;
  float sf = s[g], zf = z[g];
  __half2 s2 = __float2half2_rn(sf), nzs = __float2half2_rn(-zf * sf);
  f16* op = out + (size_t)g * 64;
#pragma unroll
  for (int i = 0; i < 8; ++i) {
    uint4 w = *(const uint4*)(qp + i * 4);
    uint4 o;
    o.x = dq2(w.x, s2, nzs); o.y = dq2(w.y, s2, nzs);
    o.z = dq2(w.z, s2, nzs); o.w = dq2(w.w, s2, nzs);
    *(uint4*)(op + i * 8) = o;
  }
}

// ============================ FAST PATH =====================================
// Round-0 proven skeleton (80 KB LDS, 64 VGPR + 64 AGPR = exactly 2 blocks/CU),
// with the ONLY change: B is pre-dequantized f16, so loadB is 2x dwordx4
// (8 VGPR, was 12) and writeB is 2x ds_write_b128 (was ~56 VALU dequant).
__global__ __launch_bounds__(512, 4) void gemm_gateup_f(
    const f16* __restrict__ xh, const f16* __restrict__ wg,
    const f16* __restrict__ wu, f16* __restrict__ h) {
  extern __shared__ char smem[];
  f16* lA0 = (f16*)smem;                 // 32 KB
  f16* lA1 = (f16*)(smem + 32768);       // 32 KB
  char* lBg = smem + 65536;              // 8 KB
  char* lBu = smem + 73728;              // 8 KB
  const int tid = threadIdx.x, lane = tid & 63, wave = tid >> 6;
  // XCD-aware bijective swizzle: 2752 blocks = 8 XCD * 344; same-XCD blocks
  // get consecutive sw -> 16 bm-blocks share one bn (B panel L2-resident).
  const int bid = blockIdx.y * 16 + blockIdx.x;
  const int sw  = (bid & 7) * 344 + (bid >> 3);
  const int bm = sw & 15, bn = sw >> 4;
  const int wm = wave >> 1, wn = wave & 1;

  // ---- A staging addressing: 4 chunks/thread, rows i*64 + (tid>>3)
  const int arow0 = tid >> 3;
  const int ak8s  = (tid & 7) ^ (arow0 & 7);
  const f16* aptr = xh + (size_t)(bm * 256 + arow0) * HIDDEN + ak8s * 8;
  const int aoff = tid * 16;             // + i*8192 per chunk

  // ---- B staging addressing: 2 rows/thread of one matrix (f16 now)
  const int mat = tid >> 8;              // 0 = gate, 1 = up (wave-uniform)
  const int t = tid & 255;
  const int brow0 = t >> 3;
  const f16* bp = (mat ? wu : wg) + (size_t)(bn * 64 + brow0) * HIDDEN + (t & 7) * 8;
  char* lb = mat ? lBu : lBg;
  const int bws0 = brow0 * 128 + (((t & 7) ^ (brow0 & 7)) << 4);

  // ---- fragment-read addressing
  int abase[4], asel[4];
#pragma unroll
  for (int im = 0; im < 4; ++im) {
    int r = wm * 64 + im * 16 + (lane & 15);
    abase[im] = r * 128; asel[im] = r & 7;
  }
  int bbase[2], bsel[2];
#pragma unroll
  for (int in_ = 0; in_ < 2; ++in_) {
    int r = wn * 32 + in_ * 16 + (lane & 15);
    bbase[in_] = r * 128; bsel[in_] = r & 7;
  }
  const int kchunk = lane >> 4;

  f32x4 accg[4][2] = {};
  f32x4 accu[4][2] = {};

  auto stageA = [&](const f16* src, f16* dst) {
#pragma unroll
    for (int i = 0; i < 4; ++i)
      g2lds16(src + (size_t)i * 64 * HIDDEN, (char*)dst + aoff + i * 8192);
  };
  auto loadB = [&](int ktn, uint4& w0, uint4& w1) {
    w0 = *(const uint4*)(bp + (size_t)ktn * 64);
    w1 = *(const uint4*)(bp + (size_t)32 * HIDDEN + (size_t)ktn * 64);
  };
  auto writeB = [&](uint4 w0, uint4 w1) {
    *(uint4*)(lb + bws0) = w0;
    *(uint4*)(lb + bws0 + 32 * 128) = w1;
  };
  auto compute = [&](const f16* lA) {
#pragma unroll
    for (int ks = 0; ks < 2; ++ks) {
      int kc = ks * 4 + kchunk;
      f16x8 a[4], bg[2], bu[2];
#pragma unroll
      for (int im = 0; im < 4; ++im)
        a[im] = *(const f16x8*)((const char*)lA + abase[im] + ((kc ^ asel[im]) << 4));
#pragma unroll
      for (int in_ = 0; in_ < 2; ++in_) {
        bg[in_] = *(const f16x8*)(lBg + bbase[in_] + ((kc ^ bsel[in_]) << 4));
        bu[in_] = *(const f16x8*)(lBu + bbase[in_] + ((kc ^ bsel[in_]) << 4));
      }
#pragma unroll
      for (int im = 0; im < 4; ++im)
#pragma unroll
        for (int in_ = 0; in_ < 2; ++in_) {
          accg[im][in_] = __builtin_amdgcn_mfma_f32_16x16x32_f16(a[im], bg[in_], accg[im][in_], 0, 0, 0);
          accu[im][in_] = __builtin_amdgcn_mfma_f32_16x16x32_f16(a[im], bu[in_], accu[im][in_], 0, 0, 0);
        }
    }
  };

  // ---- prologue
  stageA(aptr, lA0);
  {
    uint4 w0, w1;
    loadB(0, w0, w1);
    writeB(w0, w1);
  }
  __syncthreads();

  // ---- pipelined main loop (round-0 structure; serial region is now tiny)
  for (int kt = 0; kt < NG1 - 1; ++kt) {
    stageA(aptr + (size_t)(kt + 1) * 64, (kt & 1) ? lA0 : lA1);  // A(kt+1) DMA
    uint4 w0, w1;
    loadB(kt + 1, w0, w1);                                       // B(kt+1) -> regs
    compute((kt & 1) ? lA1 : lA0);                               // tile kt
    __syncthreads();   // (a) drains A(kt+1)/B(kt+1) loads (flew during compute)
    writeB(w0, w1);                                              // 2 ds_write only
    __syncthreads();   // (b) lgkm only
  }
  compute(((NG1 - 1) & 1) ? lA1 : lA0);

  // ---- epilogue: h = silu(g)*u, f16.  C/D: col=lane&15, row=(lane>>4)*4+r
#pragma unroll
  for (int im = 0; im < 4; ++im)
#pragma unroll
    for (int in_ = 0; in_ < 2; ++in_)
#pragma unroll
      for (int r = 0; r < 4; ++r) {
        int row = bm * 256 + wm * 64 + im * 16 + (lane >> 4) * 4 + r;
        int col = bn * 64 + wn * 32 + in_ * 16 + (lane & 15);
        float g = accg[im][in_][r];
        float u = accu[im][in_][r];
        float hv = (g / (1.0f + __expf(-g))) * u;
        h[(size_t)row * INTER + col] = (f16)hv;
      }
}

__global__ __launch_bounds__(512, 4) void gemm_down_f(
    const f16* __restrict__ h, const f16* __restrict__ wd,
    float* __restrict__ out) {
  extern __shared__ char smem[];
  f16* lA0 = (f16*)smem;
  f16* lA1 = (f16*)(smem + 32768);
  char* lB = smem + 65536;               // 16 KB
  const int tid = threadIdx.x, lane = tid & 63, wave = tid >> 6;
  // XCD swizzle: 512 blocks = 8 * 64
  const int bid = blockIdx.y * 16 + blockIdx.x;
  const int sw  = (bid & 7) * 64 + (bid >> 3);
  const int bm = sw & 15, bn = sw >> 4;
  const int wm = wave >> 1, wn = wave & 1;

  const int arow0 = tid >> 3;
  const int ak8s  = (tid & 7) ^ (arow0 & 7);
  const f16* aptr = h + (size_t)(bm * 256 + arow0) * INTER + ak8s * 8;
  const int aoff = tid * 16;

  const int brow0 = tid >> 3;                       // rows brow0 & brow0+64
  const f16* bp = wd + (size_t)(bn * 128 + brow0) * INTER + (tid & 7) * 8;
  const int bws0 = brow0 * 128 + (((tid & 7) ^ (brow0 & 7)) << 4);

  int abase[4], asel[4];
#pragma unroll
  for (int im = 0; im < 4; ++im) {
    int r = wm * 64 + im * 16 + (lane & 15);
    abase[im] = r * 128; asel[im] = r & 7;
  }
  int bbase[4], bsel[4];
#pragma unroll
  for (int in_ = 0; in_ < 4; ++in_) {
    int r = wn * 64 + in_ * 16 + (lane & 15);
    bbase[in_] = r * 128; bsel[in_] = r & 7;
  }
  const int kchunk = lane >> 4;

  f32x4 acc[4][4] = {};

  auto stageA = [&](const f16* src, f16* dst) {
#pragma unroll
    for (int i = 0; i < 4; ++i)
      g2lds16(src + (size_t)i * 64 * INTER, (char*)dst + aoff + i * 8192);
  };
  auto loadB = [&](int ktn, uint4& w0, uint4& w1) {
    w0 = *(const uint4*)(bp + (size_t)ktn * 64);
    w1 = *(const uint4*)(bp + (size_t)64 * INTER + (size_t)ktn * 64);
  };
  auto writeB = [&](uint4 w0, uint4 w1) {
    *(uint4*)(lB + bws0) = w0;
    *(uint4*)(lB + bws0 + 64 * 128) = w1;
  };
  auto compute = [&](const f16* lA) {
#pragma unroll
    for (int ks = 0; ks < 2; ++ks) {
      int kc = ks * 4 + kchunk;
      f16x8 a[4], b[4];
#pragma unroll
      for (int im = 0; im < 4; ++im)
        a[im] = *(const f16x8*)((const char*)lA + abase[im] + ((kc ^ asel[im]) << 4));
#pragma unroll
      for (int in_ = 0; in_ < 4; ++in_)
        b[in_] = *(const f16x8*)(lB + bbase[in_] + ((kc ^ bsel[in_]) << 4));
#pragma unroll
      for (int im = 0; im < 4; ++im)
#pragma unroll
        for (int in_ = 0; in_ < 4; ++in_)
          acc[im][in_] = __builtin_amdgcn_mfma_f32_16x16x32_f16(a[im], b[in_], acc[im][in_], 0, 0, 0);
    }
  };

  stageA(aptr, lA0);
  {
    uint4 w0, w1;
    loadB(0, w0, w1);
    writeB(w0, w1);
  }
  __syncthreads();

  for (int kt = 0; kt < NG2 - 1; ++kt) {
    stageA(aptr + (size_t)(kt + 1) * 64, (kt & 1) ? lA0 : lA1);
    uint4 w0, w1;
    loadB(kt + 1, w0, w1);
    compute((kt & 1) ? lA1 : lA0);
    __syncthreads();
    writeB(w0, w1);
    __syncthreads();
  }
  compute(((NG2 - 1) & 1) ? lA1 : lA0);

#pragma unroll
  for (int im = 0; im < 4; ++im)
#pragma unroll
    for (int in_ = 0; in_ < 4; ++in_)
#pragma unroll
      for (int r = 0; r < 4; ++r) {
        int row = bm * 256 + wm * 64 + im * 16 + (lane >> 4) * 4 + r;
        int col = bn * 128 + wn * 64 + in_ * 16 + (lane & 15);
        out[(size_t)row * HIDDEN + col] = acc[im][in_][r];
      }
}

// ============================ FALLBACK PATH (round-0 verbatim, 1501 us) ======
__global__ __launch_bounds__(512, 4) void gemm_gateup_q(
    const f16* __restrict__ xh,
    const uint32_t* __restrict__ gq, const uint32_t* __restrict__ uq,
    const float* __restrict__ gs, const float* __restrict__ gz,
    const float* __restrict__ us, const float* __restrict__ uz,
    f16* __restrict__ h) {
  extern __shared__ char smem[];
  f16* lA0 = (f16*)smem;
  f16* lA1 = (f16*)(smem + 32768);
  char* lBg = smem + 65536;
  char* lBu = smem + 73728;
  const int tid = threadIdx.x, lane = tid & 63, wave = tid >> 6;
  const int bm = blockIdx.x, bn = blockIdx.y;
  const int wm = wave >> 1, wn = wave & 1;

  const int arow0 = tid >> 3;
  const int ak8s  = (tid & 7) ^ (arow0 & 7);
  const f16* aptr = xh + (size_t)(bm * 256 + arow0) * HIDDEN + ak8s * 8;
  const int aoff = tid * 16;

  const int mat = tid >> 8;
  const int t = tid & 255;
  const int brow0 = t >> 3;
  const uint32_t* qp = (mat ? uq : gq) + (size_t)(bn * 64 + brow0) * (HIDDEN / 2) + (t & 7) * 4;
  const float* sp = (mat ? us : gs) + (size_t)(bn * 64 + brow0) * NG1;
  const float* zp = (mat ? uz : gz) + (size_t)(bn * 64 + brow0) * NG1;
  char* lb = mat ? lBu : lBg;
  const int bws0 = brow0 * 128 + (((t & 7) ^ (brow0 & 7)) << 4);

  int abase[4], asel[4];
#pragma unroll
  for (int im = 0; im < 4; ++im) {
    int r = wm * 64 + im * 16 + (lane & 15);
    abase[im] = r * 128; asel[im] = r & 7;
  }
  int bbase[2], bsel[2];
#pragma unroll
  for (int in_ = 0; in_ < 2; ++in_) {
    int r = wn * 32 + in_ * 16 + (lane & 15);
    bbase[in_] = r * 128; bsel[in_] = r & 7;
  }
  const int kchunk = lane >> 4;

  f32x4 accg[4][2] = {};
  f32x4 accu[4][2] = {};

  auto stageA = [&](const f16* src, f16* dst) {
#pragma unroll
    for (int i = 0; i < 4; ++i)
      g2lds16(src + (size_t)i * 64 * HIDDEN, (char*)dst + aoff + i * 8192);
  };
  auto loadB = [&](int ktn, uint4& w0, uint4& w1,
                   float& s0f, float& z0f, float& s1f, float& z1f) {
    w0 = *(const uint4*)(qp + (size_t)ktn * 32);
    w1 = *(const uint4*)(qp + (size_t)32 * (HIDDEN / 2) + (size_t)ktn * 32);
    s0f = sp[ktn]; z0f = zp[ktn];
    s1f = sp[32 * NG1 + ktn]; z1f = zp[32 * NG1 + ktn];
  };
  auto writeB = [&](uint4 w0, uint4 w1, float s0f, float z0f, float s1f, float z1f) {
    __half2 s0 = __float2half2_rn(s0f), n0 = __float2half2_rn(-z0f * s0f);
    __half2 s1 = __float2half2_rn(s1f), n1 = __float2half2_rn(-z1f * s1f);
    uint4 o0, o1;
    o0.x = dq2(w0.x, s0, n0); o0.y = dq2(w0.y, s0, n0);
    o0.z = dq2(w0.z, s0, n0); o0.w = dq2(w0.w, s0, n0);
    o1.x = dq2(w1.x, s1, n1); o1.y = dq2(w1.y, s1, n1);
    o1.z = dq2(w1.z, s1, n1); o1.w = dq2(w1.w, s1, n1);
    *(uint4*)(lb + bws0) = o0;
    *(uint4*)(lb + bws0 + 32 * 128) = o1;
  };
  auto compute = [&](const f16* lA) {
#pragma unroll
    for (int ks = 0; ks < 2; ++ks) {
      int kc = ks * 4 + kchunk;
      f16x8 a[4], bg[2], bu[2];
#pragma unroll
      for (int im = 0; im < 4; ++im)
        a[im] = *(const f16x8*)((const char*)lA + abase[im] + ((kc ^ asel[im]) << 4));
#pragma unroll
      for (int in_ = 0; in_ < 2; ++in_) {
        bg[in_] = *(const f16x8*)(lBg + bbase[in_] + ((kc ^ bsel[in_]) << 4));
        bu[in_] = *(const f16x8*)(lBu + bbase[in_] + ((kc ^ bsel[in_]) << 4));
      }
#pragma unroll
      for (int im = 0; im < 4; ++im)
#pragma unroll
        for (int in_ = 0; in_ < 2; ++in_) {
          accg[im][in_] = __builtin_amdgcn_mfma_f32_16x16x32_f16(a[im], bg[in_], accg[im][in_], 0, 0, 0);
          accu[im][in_] = __builtin_amdgcn_mfma_f32_16x16x32_f16(a[im], bu[in_], accu[im][in_], 0, 0, 0);
        }
    }
  };

  stageA(aptr, lA0);
  {
    uint4 w0, w1; float s0f, z0f, s1f, z1f;
    loadB(0, w0, w1, s0f, z0f, s1f, z1f);
    writeB(w0, w1, s0f, z0f, s1f, z1f);
  }
  __syncthreads();

  for (int kt = 0; kt < NG1 - 1; ++kt) {
    stageA(aptr + (size_t)(kt + 1) * 64, (kt & 1) ? lA0 : lA1);
    uint4 w0, w1; float s0f, z0f, s1f, z1f;
    loadB(kt + 1, w0, w1, s0f, z0f, s1f, z1f);
    compute((kt & 1) ? lA1 : lA0);
    __syncthreads();
    writeB(w0, w1, s0f, z0f, s1f, z1f);
    __syncthreads();
  }
  compute(((NG1 - 1) & 1) ? lA1 : lA0);

#pragma unroll
  for (int im = 0; im < 4; ++im)
#pragma unroll
    for (int in_ = 0; in_ < 2; ++in_)
#pragma unroll
      for (int r = 0; r < 4; ++r) {
        int row = bm * 256 + wm * 64 + im * 16 + (lane >> 4) * 4 + r;
        int col = bn * 64 + wn * 32 + in_ * 16 + (lane & 15);
        float g = accg[im][in_][r];
        float u = accu[im][in_][r];
        float hv = (g / (1.0f + __expf(-g))) * u;
        h[(size_t)row * INTER + col] = (f16)hv;
      }
}

__global__ __launch_bounds__(512, 4) void gemm_down_q(
    const f16* __restrict__ h, const uint32_t* __restrict__ dq_,
    const float* __restrict__ dsc, const float* __restrict__ dz,
    float* __restrict__ out) {
  extern __shared__ char smem[];
  f16* lA0 = (f16*)smem;
  f16* lA1 = (f16*)(smem + 32768);
  char* lB = smem + 65536;
  const int tid = threadIdx.x, lane = tid & 63, wave = tid >> 6;
  const int bm = blockIdx.x, bn = blockIdx.y;
  const int wm = wave >> 1, wn = wave & 1;

  const int arow0 = tid >> 3;
  const int ak8s  = (tid & 7) ^ (arow0 & 7);
  const f16* aptr = h + (size_t)(bm * 256 + arow0) * INTER + ak8s * 8;
  const int aoff = tid * 16;

  const int brow0 = tid >> 3;
  const uint32_t* qp = dq_ + (size_t)(bn * 128 + brow0) * (INTER / 2) + (tid & 7) * 4;
  const float* sp = dsc + (size_t)(bn * 128 + brow0) * NG2;
  const float* zp = dz + (size_t)(bn * 128 + brow0) * NG2;
  const int bws0 = brow0 * 128 + (((tid & 7) ^ (brow0 & 7)) << 4);

  int abase[4], asel[4];
#pragma unroll
  for (int im = 0; im < 4; ++im) {
    int r = wm * 64 + im * 16 + (lane & 15);
    abase[im] = r * 128; asel[im] = r & 7;
  }
  int bbase[4], bsel[4];
#pragma unroll
  for (int in_ = 0; in_ < 4; ++in_) {
    int r = wn * 64 + in_ * 16 + (lane & 15);
    bbase[in_] = r * 128; bsel[in_] = r & 7;
  }
  const int kchunk = lane >> 4;

  f32x4 acc[4][4] = {};

  auto stageA = [&](const f16* src, f16* dst) {
#pragma unroll
    for (int i = 0; i < 4; ++i)
      g2lds16(src + (size_t)i * 64 * INTER, (char*)dst + aoff + i * 8192);
  };
  auto loadB = [&](int ktn, uint4& w0, uint4& w1,
                   float& s0f, float& z0f, float& s1f, float& z1f) {
    w0 = *(const uint4*)(qp + (size_t)ktn * 32);
    w1 = *(const uint4*)(qp + (size_t)64 * (INTER / 2) + (size_t)ktn * 32);
    s0f = sp[ktn]; z0f = zp[ktn];
    s1f = sp[64 * NG2 + ktn]; z1f = zp[64 * NG2 + ktn];
  };
  auto writeB = [&](uint4 w0, uint4 w1, float s0f, float z0f, float s1f, float z1f) {
    __half2 s0 = __float2half2_rn(s0f), n0 = __float2half2_rn(-z0f * s0f);
    __half2 s1 = __float2half2_rn(s1f), n1 = __float2half2_rn(-z1f * s1f);
    uint4 o0, o1;
    o0.x = dq2(w0.x, s0, n0); o0.y = dq2(w0.y, s0, n0);
    o0.z = dq2(w0.z, s0, n0); o0.w = dq2(w0.w, s0, n0);
    o1.x = dq2(w1.x, s1, n1); o1.y = dq2(w1.y, s1, n1);
    o1.z = dq2(w1.z, s1, n1); o1.w = dq2(w1.w, s1, n1);
    *(uint4*)(lB + bws0) = o0;
    *(uint4*)(lB + bws0 + 64 * 128) = o1;
  };
  auto compute = [&](const f16* lA) {
#pragma unroll
    for (int ks = 0; ks < 2; ++ks) {
      int kc = ks * 4 + kchunk;
      f16x8 a[4], b[4];
#pragma unroll
      for (int im = 0; im < 4; ++im)
        a[im] = *(const f16x8*)((const char*)lA + abase[im] + ((kc ^ asel[im]) << 4));
#pragma unroll
      for (int in_ = 0; in_ < 4; ++in_)
        b[in_] = *(const f16x8*)(lB + bbase[in_] + ((kc ^ bsel[in_]) << 4));
#pragma unroll
      for (int im = 0; im < 4; ++im)
#pragma unroll
        for (int in_ = 0; in_ < 4; ++in_)
          acc[im][in_] = __builtin_amdgcn_mfma_f32_16x16x32_f16(a[im], b[in_], acc[im][in_], 0, 0, 0);
    }
  };

  stageA(aptr, lA0);
  {
    uint4 w0, w1; float s0f, z0f, s1f, z1f;
    loadB(0, w0, w1, s0f, z0f, s1f, z1f);
    writeB(w0, w1, s0f, z0f, s1f, z1f);
  }
  __syncthreads();

  for (int kt = 0; kt < NG2 - 1; ++kt) {
    stageA(aptr + (size_t)(kt + 1) * 64, (kt & 1) ? lA0 : lA1);
    uint4 w0, w1; float s0f, z0f, s1f, z1f;
    loadB(kt + 1, w0, w1, s0f, z0f, s1f, z1f);
    compute((kt & 1) ? lA1 : lA0);
    __syncthreads();
    writeB(w0, w1, s0f, z0f, s1f, z1f);
    __syncthreads();
  }
  compute(((NG2 - 1) & 1) ? lA1 : lA0);

#pragma unroll
  for (int im = 0; im < 4; ++im)
#pragma unroll
    for (int in_ = 0; in_ < 4; ++in_)
#pragma unroll
      for (int r = 0; r < 4; ++r) {
        int row = bm * 256 + wm * 64 + im * 16 + (lane >> 4) * 4 + r;
        int col = bn * 128 + wn * 64 + in_ * 16 + (lane & 15);
        out[(size_t)row * HIDDEN + col] = acc[im][in_][r];
      }
}

// ------------------------------------------------------------------- launcher
extern "C" void kernel_launch(void* const* d_in, const int* in_sizes, int n_in,
                              void* d_out, int out_size, void* d_ws, size_t ws_size,
                              hipStream_t stream) {
  const float*    x   = (const float*)d_in[0];
  const uint32_t* gq  = (const uint32_t*)d_in[1];
  const uint32_t* uq  = (const uint32_t*)d_in[2];
  const uint32_t* dqw = (const uint32_t*)d_in[3];
  const float*    gs  = (const float*)d_in[4];
  const float*    gz  = (const float*)d_in[5];
  const float*    us  = (const float*)d_in[6];
  const float*    uz  = (const float*)d_in[7];
  const float*    dsc = (const float*)d_in[8];
  const float*    dzz = (const float*)d_in[9];

  const size_t XH = (size_t)NTOK * HIDDEN * 2;          // 33.6 MB
  const size_t HB = (size_t)NTOK * INTER * 2;           // 90.2 MB
  const size_t WB = (size_t)INTER * HIDDEN * 2;         // 90.2 MB
  f16* xh   = (f16*)d_ws;
  f16* hbuf = (f16*)((char*)d_ws + XH);
  float* out = (float*)d_out;

  const int LDS_BYTES = 80 * 1024;

  cvt_x<<<dim3((NTOK * HIDDEN) / (256 * 8)), 256, 0, stream>>>(x, xh);

  if (ws_size >= XH + HB + 2 * WB) {
    // fast path: dequant each weight once, f16-B GEMMs (round-0 skeleton)
    f16* W1 = (f16*)((char*)d_ws + XH + HB);            // gate, later down
    f16* W2 = (f16*)((char*)d_ws + XH + HB + WB);       // up
    (void)hipFuncSetAttribute((const void*)gemm_gateup_f,
                              hipFuncAttributeMaxDynamicSharedMemorySize, LDS_BYTES);
    (void)hipFuncSetAttribute((const void*)gemm_down_f,
                              hipFuncAttributeMaxDynamicSharedMemorySize, LDS_BYTES);
    deq_w<<<dim3((INTER * NG1) / 256), 256, 0, stream>>>(gq, gs, gz, W1);
    deq_w<<<dim3((INTER * NG1) / 256), 256, 0, stream>>>(uq, us, uz, W2);
    gemm_gateup_f<<<dim3(NTOK / 256, INTER / 64), 512, LDS_BYTES, stream>>>(
        xh, W1, W2, hbuf);
    deq_w<<<dim3((HIDDEN * NG2) / 256), 256, 0, stream>>>(dqw, dsc, dzz, W1);
    gemm_down_f<<<dim3(NTOK / 256, HIDDEN / 128), 512, LDS_BYTES, stream>>>(
        hbuf, W1, out);
  } else {
    // fallback: round-0 proven kernels (dequant in-GEMM)
    (void)hipFuncSetAttribute((const void*)gemm_gateup_q,
                              hipFuncAttributeMaxDynamicSharedMemorySize, LDS_BYTES);
    (void)hipFuncSetAttribute((const void*)gemm_down_q,
                              hipFuncAttributeMaxDynamicSharedMemorySize, LDS_BYTES);
    gemm_gateup_q<<<dim3(NTOK / 256, INTER / 64), 512, LDS_BYTES, stream>>>(
        xh, gq, uq, gs, gz, us, uz, hbuf);
    gemm_down_q<<<dim3(NTOK / 256, HIDDEN / 128), 512, LDS_BYTES, stream>>>(
        hbuf, dqw, dsc, dzz, out);
  }
}

// Round 5
// 1436.779 us; speedup vs baseline: 2.7772x; 1.0694x over previous
//
#include <hip/hip_runtime.h>
#include <hip/hip_fp16.h>
#include <cstdint>
#include <cstddef>

// Problem constants (fixed by the reference)
#define HIDDEN 4096
#define INTER  11008
#define NTOK   4096          // B*S = 4*1024
#define NG1    (HIDDEN/64)   // 64 groups along hidden
#define NG2    (INTER/64)    // 172 groups along inter

typedef _Float16 f16;
typedef _Float16 f16x8 __attribute__((ext_vector_type(8)));
typedef float    f32x4 __attribute__((ext_vector_type(4)));

// ---- async global->LDS, 16B per lane (dest must be wave-uniform base + lane*16)
__device__ __forceinline__ void g2lds16(const void* g, void* l) {
  __builtin_amdgcn_global_load_lds(
      (const __attribute__((address_space(1))) uint32_t*)g,
      (__attribute__((address_space(3))) uint32_t*)l, 16, 0, 0);
}

// ---- lgkm-only workgroup barrier: does NOT drain vmcnt, so in-flight
// global_load_lds DMAs and register loads keep flying across it. Used at
// barrier (a), where the only requirement is "all waves done READING lB".
__device__ __forceinline__ void bar_lgkm() {
  asm volatile("s_waitcnt lgkmcnt(0)" ::: "memory");
  __builtin_amdgcn_s_barrier();
  asm volatile("" ::: "memory");
}

// ---- dequant one storage int32 (value in [0,256) = 2 nibbles) -> 2 f16
// w = (q - z) * s via exact f16 exponent trick + single pk_fma.
__device__ __forceinline__ uint32_t dq2(uint32_t b, __half2 s2, __half2 nzs) {
  uint32_t qb = 0x64006400u | (b >> 4) | ((b & 0xFu) << 16);
  __half2 hq = __builtin_bit_cast(__half2, qb);
  __half2 t  = __hsub2(hq, __builtin_bit_cast(__half2, 0x64006400u));
  __half2 wv = __hfma2(t, s2, nzs);
  return __builtin_bit_cast(uint32_t, wv);
}

// ---------------------------------------------------------------- x: fp32->f16
__global__ __launch_bounds__(256) void cvt_x(const float* __restrict__ x,
                                             f16* __restrict__ xh) {
  size_t i = ((size_t)blockIdx.x * 256 + threadIdx.x) * 8;
  float4 a = *(const float4*)(x + i);
  float4 b = *(const float4*)(x + i + 4);
  f16x8 o = {(f16)a.x, (f16)a.y, (f16)a.z, (f16)a.w,
             (f16)b.x, (f16)b.y, (f16)b.z, (f16)b.w};
  *(f16x8*)(xh + i) = o;
}

// ---------------------------------------------- weight dequant pass (once)
// One thread = one quant group (64 weights = 32 packed int32). Memory-bound.
__global__ __launch_bounds__(256) void deq_w(const uint32_t* __restrict__ q,
                                             const float* __restrict__ s,
                                             const float* __restrict__ z,
                                             f16* __restrict__ out) {
  int g = blockIdx.x * 256 + threadIdx.x;
  const uint32_t* qp = q + (size_t)g * 32;
  float sf = s[g], zf = z[g];
  __half2 s2 = __float2half2_rn(sf), nzs = __float2half2_rn(-zf * sf);
  f16* op = out + (size_t)g * 64;
#pragma unroll
  for (int i = 0; i < 8; ++i) {
    uint4 w = *(const uint4*)(qp + i * 4);
    uint4 o;
    o.x = dq2(w.x, s2, nzs); o.y = dq2(w.y, s2, nzs);
    o.z = dq2(w.z, s2, nzs); o.w = dq2(w.w, s2, nzs);
    *(uint4*)(op + i * 8) = o;
  }
}

// ============================ FAST PATH =====================================
// Round-4 skeleton (80 KB LDS, 64 VGPR + 64 AGPR = exactly 2 blocks/CU) with:
//  * NO XCD swizzle (round-4 lesson: default dispatch gives 2bm x 32bn per
//    XCD -> A tiles L2-resident; my swizzle forced 16bm x 4bn -> 2.2 GB fetch)
//  * late-wait barriers: loadB issued BEFORE stageA (writeB dep-waits
//    vmcnt(4), not a drain); barrier (a) lgkm-only (A-DMAs fly through);
//    barrier (b) = __syncthreads (vmcnt(0) exact: only the A-DMAs remain).
__global__ __launch_bounds__(512, 4) void gemm_gateup_f(
    const f16* __restrict__ xh, const f16* __restrict__ wg,
    const f16* __restrict__ wu, f16* __restrict__ h) {
  extern __shared__ char smem[];
  f16* lA0 = (f16*)smem;                 // 32 KB
  f16* lA1 = (f16*)(smem + 32768);       // 32 KB
  char* lBg = smem + 65536;              // 8 KB
  char* lBu = smem + 73728;              // 8 KB
  const int tid = threadIdx.x, lane = tid & 63, wave = tid >> 6;
  const int bm = blockIdx.x, bn = blockIdx.y;      // default mapping (no swizzle)
  const int wm = wave >> 1, wn = wave & 1;

  // ---- A staging addressing: 4 chunks/thread, rows i*64 + (tid>>3)
  const int arow0 = tid >> 3;
  const int ak8s  = (tid & 7) ^ (arow0 & 7);
  const f16* aptr = xh + (size_t)(bm * 256 + arow0) * HIDDEN + ak8s * 8;
  const int aoff = tid * 16;             // + i*8192 per chunk

  // ---- B staging addressing: 2 rows/thread of one matrix (f16)
  const int mat = tid >> 8;              // 0 = gate, 1 = up (wave-uniform)
  const int t = tid & 255;
  const int brow0 = t >> 3;
  const f16* bp = (mat ? wu : wg) + (size_t)(bn * 64 + brow0) * HIDDEN + (t & 7) * 8;
  char* lb = mat ? lBu : lBg;
  const int bws0 = brow0 * 128 + (((t & 7) ^ (brow0 & 7)) << 4);

  // ---- fragment-read addressing
  int abase[4], asel[4];
#pragma unroll
  for (int im = 0; im < 4; ++im) {
    int r = wm * 64 + im * 16 + (lane & 15);
    abase[im] = r * 128; asel[im] = r & 7;
  }
  int bbase[2], bsel[2];
#pragma unroll
  for (int in_ = 0; in_ < 2; ++in_) {
    int r = wn * 32 + in_ * 16 + (lane & 15);
    bbase[in_] = r * 128; bsel[in_] = r & 7;
  }
  const int kchunk = lane >> 4;

  f32x4 accg[4][2] = {};
  f32x4 accu[4][2] = {};

  auto stageA = [&](const f16* src, f16* dst) {
#pragma unroll
    for (int i = 0; i < 4; ++i)
      g2lds16(src + (size_t)i * 64 * HIDDEN, (char*)dst + aoff + i * 8192);
  };
  auto loadB = [&](int ktn, uint4& w0, uint4& w1) {
    w0 = *(const uint4*)(bp + (size_t)ktn * 64);
    w1 = *(const uint4*)(bp + (size_t)32 * HIDDEN + (size_t)ktn * 64);
  };
  auto writeB = [&](uint4 w0, uint4 w1) {
    *(uint4*)(lb + bws0) = w0;
    *(uint4*)(lb + bws0 + 32 * 128) = w1;
  };
  auto compute = [&](const f16* lA) {
#pragma unroll
    for (int ks = 0; ks < 2; ++ks) {
      int kc = ks * 4 + kchunk;
      f16x8 a[4], bg[2], bu[2];
#pragma unroll
      for (int im = 0; im < 4; ++im)
        a[im] = *(const f16x8*)((const char*)lA + abase[im] + ((kc ^ asel[im]) << 4));
#pragma unroll
      for (int in_ = 0; in_ < 2; ++in_) {
        bg[in_] = *(const f16x8*)(lBg + bbase[in_] + ((kc ^ bsel[in_]) << 4));
        bu[in_] = *(const f16x8*)(lBu + bbase[in_] + ((kc ^ bsel[in_]) << 4));
      }
#pragma unroll
      for (int im = 0; im < 4; ++im)
#pragma unroll
        for (int in_ = 0; in_ < 2; ++in_) {
          accg[im][in_] = __builtin_amdgcn_mfma_f32_16x16x32_f16(a[im], bg[in_], accg[im][in_], 0, 0, 0);
          accu[im][in_] = __builtin_amdgcn_mfma_f32_16x16x32_f16(a[im], bu[in_], accu[im][in_], 0, 0, 0);
        }
    }
  };

  // ---- prologue (loads first so writeB dep-waits vmcnt(4))
  {
    uint4 w0, w1;
    loadB(0, w0, w1);
    stageA(aptr, lA0);
    writeB(w0, w1);
  }
  __syncthreads();

  // ---- main loop: late-wait two-barrier K-step
  for (int kt = 0; kt < NG1 - 1; ++kt) {
    uint4 w0, w1;
    loadB(kt + 1, w0, w1);                                       // 2 VMEM (oldest of B)
    stageA(aptr + (size_t)(kt + 1) * 64, (kt & 1) ? lA0 : lA1);  // 4 DMA
    __builtin_amdgcn_sched_barrier(0);                           // pin loads first
    compute((kt & 1) ? lA1 : lA0);                               // tile kt
    bar_lgkm();          // (a) all lB readers done; DMAs + B loads keep flying
    writeB(w0, w1);      //     auto s_waitcnt vmcnt(4): B regs ready, DMAs fly
    __syncthreads();     // (b) vmcnt(0)+lgkm: A(kt+1) in LDS, writeB visible
  }
  compute(((NG1 - 1) & 1) ? lA1 : lA0);

  // ---- epilogue: h = silu(g)*u, f16.  C/D: col=lane&15, row=(lane>>4)*4+r
#pragma unroll
  for (int im = 0; im < 4; ++im)
#pragma unroll
    for (int in_ = 0; in_ < 2; ++in_)
#pragma unroll
      for (int r = 0; r < 4; ++r) {
        int row = bm * 256 + wm * 64 + im * 16 + (lane >> 4) * 4 + r;
        int col = bn * 64 + wn * 32 + in_ * 16 + (lane & 15);
        float g = accg[im][in_][r];
        float u = accu[im][in_][r];
        float hv = (g / (1.0f + __expf(-g))) * u;
        h[(size_t)row * INTER + col] = (f16)hv;
      }
}

__global__ __launch_bounds__(512, 4) void gemm_down_f(
    const f16* __restrict__ h, const f16* __restrict__ wd,
    float* __restrict__ out) {
  extern __shared__ char smem[];
  f16* lA0 = (f16*)smem;
  f16* lA1 = (f16*)(smem + 32768);
  char* lB = smem + 65536;               // 16 KB
  const int tid = threadIdx.x, lane = tid & 63, wave = tid >> 6;
  const int bm = blockIdx.x, bn = blockIdx.y;      // default mapping (no swizzle)
  const int wm = wave >> 1, wn = wave & 1;

  const int arow0 = tid >> 3;
  const int ak8s  = (tid & 7) ^ (arow0 & 7);
  const f16* aptr = h + (size_t)(bm * 256 + arow0) * INTER + ak8s * 8;
  const int aoff = tid * 16;

  const int brow0 = tid >> 3;                       // rows brow0 & brow0+64
  const f16* bp = wd + (size_t)(bn * 128 + brow0) * INTER + (tid & 7) * 8;
  const int bws0 = brow0 * 128 + (((tid & 7) ^ (brow0 & 7)) << 4);

  int abase[4], asel[4];
#pragma unroll
  for (int im = 0; im < 4; ++im) {
    int r = wm * 64 + im * 16 + (lane & 15);
    abase[im] = r * 128; asel[im] = r & 7;
  }
  int bbase[4], bsel[4];
#pragma unroll
  for (int in_ = 0; in_ < 4; ++in_) {
    int r = wn * 64 + in_ * 16 + (lane & 15);
    bbase[in_] = r * 128; bsel[in_] = r & 7;
  }
  const int kchunk = lane >> 4;

  f32x4 acc[4][4] = {};

  auto stageA = [&](const f16* src, f16* dst) {
#pragma unroll
    for (int i = 0; i < 4; ++i)
      g2lds16(src + (size_t)i * 64 * INTER, (char*)dst + aoff + i * 8192);
  };
  auto loadB = [&](int ktn, uint4& w0, uint4& w1) {
    w0 = *(const uint4*)(bp + (size_t)ktn * 64);
    w1 = *(const uint4*)(bp + (size_t)64 * INTER + (size_t)ktn * 64);
  };
  auto writeB = [&](uint4 w0, uint4 w1) {
    *(uint4*)(lB + bws0) = w0;
    *(uint4*)(lB + bws0 + 64 * 128) = w1;
  };
  auto compute = [&](const f16* lA) {
#pragma unroll
    for (int ks = 0; ks < 2; ++ks) {
      int kc = ks * 4 + kchunk;
      f16x8 a[4], b[4];
#pragma unroll
      for (int im = 0; im < 4; ++im)
        a[im] = *(const f16x8*)((const char*)lA + abase[im] + ((kc ^ asel[im]) << 4));
#pragma unroll
      for (int in_ = 0; in_ < 4; ++in_)
        b[in_] = *(const f16x8*)(lB + bbase[in_] + ((kc ^ bsel[in_]) << 4));
#pragma unroll
      for (int im = 0; im < 4; ++im)
#pragma unroll
        for (int in_ = 0; in_ < 4; ++in_)
          acc[im][in_] = __builtin_amdgcn_mfma_f32_16x16x32_f16(a[im], b[in_], acc[im][in_], 0, 0, 0);
    }
  };

  {
    uint4 w0, w1;
    loadB(0, w0, w1);
    stageA(aptr, lA0);
    writeB(w0, w1);
  }
  __syncthreads();

  for (int kt = 0; kt < NG2 - 1; ++kt) {
    uint4 w0, w1;
    loadB(kt + 1, w0, w1);
    stageA(aptr + (size_t)(kt + 1) * 64, (kt & 1) ? lA0 : lA1);
    __builtin_amdgcn_sched_barrier(0);
    compute((kt & 1) ? lA1 : lA0);
    bar_lgkm();          // (a) lgkm-only
    writeB(w0, w1);      //     vmcnt(4) dep-wait
    __syncthreads();     // (b) full
  }
  compute(((NG2 - 1) & 1) ? lA1 : lA0);

#pragma unroll
  for (int im = 0; im < 4; ++im)
#pragma unroll
    for (int in_ = 0; in_ < 4; ++in_)
#pragma unroll
      for (int r = 0; r < 4; ++r) {
        int row = bm * 256 + wm * 64 + im * 16 + (lane >> 4) * 4 + r;
        int col = bn * 128 + wn * 64 + in_ * 16 + (lane & 15);
        out[(size_t)row * HIDDEN + col] = acc[im][in_][r];
      }
}

// ============================ FALLBACK PATH (round-0 verbatim, 1501 us) ======
__global__ __launch_bounds__(512, 4) void gemm_gateup_q(
    const f16* __restrict__ xh,
    const uint32_t* __restrict__ gq, const uint32_t* __restrict__ uq,
    const float* __restrict__ gs, const float* __restrict__ gz,
    const float* __restrict__ us, const float* __restrict__ uz,
    f16* __restrict__ h) {
  extern __shared__ char smem[];
  f16* lA0 = (f16*)smem;
  f16* lA1 = (f16*)(smem + 32768);
  char* lBg = smem + 65536;
  char* lBu = smem + 73728;
  const int tid = threadIdx.x, lane = tid & 63, wave = tid >> 6;
  const int bm = blockIdx.x, bn = blockIdx.y;
  const int wm = wave >> 1, wn = wave & 1;

  const int arow0 = tid >> 3;
  const int ak8s  = (tid & 7) ^ (arow0 & 7);
  const f16* aptr = xh + (size_t)(bm * 256 + arow0) * HIDDEN + ak8s * 8;
  const int aoff = tid * 16;

  const int mat = tid >> 8;
  const int t = tid & 255;
  const int brow0 = t >> 3;
  const uint32_t* qp = (mat ? uq : gq) + (size_t)(bn * 64 + brow0) * (HIDDEN / 2) + (t & 7) * 4;
  const float* sp = (mat ? us : gs) + (size_t)(bn * 64 + brow0) * NG1;
  const float* zp = (mat ? uz : gz) + (size_t)(bn * 64 + brow0) * NG1;
  char* lb = mat ? lBu : lBg;
  const int bws0 = brow0 * 128 + (((t & 7) ^ (brow0 & 7)) << 4);

  int abase[4], asel[4];
#pragma unroll
  for (int im = 0; im < 4; ++im) {
    int r = wm * 64 + im * 16 + (lane & 15);
    abase[im] = r * 128; asel[im] = r & 7;
  }
  int bbase[2], bsel[2];
#pragma unroll
  for (int in_ = 0; in_ < 2; ++in_) {
    int r = wn * 32 + in_ * 16 + (lane & 15);
    bbase[in_] = r * 128; bsel[in_] = r & 7;
  }
  const int kchunk = lane >> 4;

  f32x4 accg[4][2] = {};
  f32x4 accu[4][2] = {};

  auto stageA = [&](const f16* src, f16* dst) {
#pragma unroll
    for (int i = 0; i < 4; ++i)
      g2lds16(src + (size_t)i * 64 * HIDDEN, (char*)dst + aoff + i * 8192);
  };
  auto loadB = [&](int ktn, uint4& w0, uint4& w1,
                   float& s0f, float& z0f, float& s1f, float& z1f) {
    w0 = *(const uint4*)(qp + (size_t)ktn * 32);
    w1 = *(const uint4*)(qp + (size_t)32 * (HIDDEN / 2) + (size_t)ktn * 32);
    s0f = sp[ktn]; z0f = zp[ktn];
    s1f = sp[32 * NG1 + ktn]; z1f = zp[32 * NG1 + ktn];
  };
  auto writeB = [&](uint4 w0, uint4 w1, float s0f, float z0f, float s1f, float z1f) {
    __half2 s0 = __float2half2_rn(s0f), n0 = __float2half2_rn(-z0f * s0f);
    __half2 s1 = __float2half2_rn(s1f), n1 = __float2half2_rn(-z1f * s1f);
    uint4 o0, o1;
    o0.x = dq2(w0.x, s0, n0); o0.y = dq2(w0.y, s0, n0);
    o0.z = dq2(w0.z, s0, n0); o0.w = dq2(w0.w, s0, n0);
    o1.x = dq2(w1.x, s1, n1); o1.y = dq2(w1.y, s1, n1);
    o1.z = dq2(w1.z, s1, n1); o1.w = dq2(w1.w, s1, n1);
    *(uint4*)(lb + bws0) = o0;
    *(uint4*)(lb + bws0 + 32 * 128) = o1;
  };
  auto compute = [&](const f16* lA) {
#pragma unroll
    for (int ks = 0; ks < 2; ++ks) {
      int kc = ks * 4 + kchunk;
      f16x8 a[4], bg[2], bu[2];
#pragma unroll
      for (int im = 0; im < 4; ++im)
        a[im] = *(const f16x8*)((const char*)lA + abase[im] + ((kc ^ asel[im]) << 4));
#pragma unroll
      for (int in_ = 0; in_ < 2; ++in_) {
        bg[in_] = *(const f16x8*)(lBg + bbase[in_] + ((kc ^ bsel[in_]) << 4));
        bu[in_] = *(const f16x8*)(lBu + bbase[in_] + ((kc ^ bsel[in_]) << 4));
      }
#pragma unroll
      for (int im = 0; im < 4; ++im)
#pragma unroll
        for (int in_ = 0; in_ < 2; ++in_) {
          accg[im][in_] = __builtin_amdgcn_mfma_f32_16x16x32_f16(a[im], bg[in_], accg[im][in_], 0, 0, 0);
          accu[im][in_] = __builtin_amdgcn_mfma_f32_16x16x32_f16(a[im], bu[in_], accu[im][in_], 0, 0, 0);
        }
    }
  };

  stageA(aptr, lA0);
  {
    uint4 w0, w1; float s0f, z0f, s1f, z1f;
    loadB(0, w0, w1, s0f, z0f, s1f, z1f);
    writeB(w0, w1, s0f, z0f, s1f, z1f);
  }
  __syncthreads();

  for (int kt = 0; kt < NG1 - 1; ++kt) {
    stageA(aptr + (size_t)(kt + 1) * 64, (kt & 1) ? lA0 : lA1);
    uint4 w0, w1; float s0f, z0f, s1f, z1f;
    loadB(kt + 1, w0, w1, s0f, z0f, s1f, z1f);
    compute((kt & 1) ? lA1 : lA0);
    __syncthreads();
    writeB(w0, w1, s0f, z0f, s1f, z1f);
    __syncthreads();
  }
  compute(((NG1 - 1) & 1) ? lA1 : lA0);

#pragma unroll
  for (int im = 0; im < 4; ++im)
#pragma unroll
    for (int in_ = 0; in_ < 2; ++in_)
#pragma unroll
      for (int r = 0; r < 4; ++r) {
        int row = bm * 256 + wm * 64 + im * 16 + (lane >> 4) * 4 + r;
        int col = bn * 64 + wn * 32 + in_ * 16 + (lane & 15);
        float g = accg[im][in_][r];
        float u = accu[im][in_][r];
        float hv = (g / (1.0f + __expf(-g))) * u;
        h[(size_t)row * INTER + col] = (f16)hv;
      }
}

__global__ __launch_bounds__(512, 4) void gemm_down_q(
    const f16* __restrict__ h, const uint32_t* __restrict__ dq_,
    const float* __restrict__ dsc, const float* __restrict__ dz,
    float* __restrict__ out) {
  extern __shared__ char smem[];
  f16* lA0 = (f16*)smem;
  f16* lA1 = (f16*)(smem + 32768);
  char* lB = smem + 65536;
  const int tid = threadIdx.x, lane = tid & 63, wave = tid >> 6;
  const int bm = blockIdx.x, bn = blockIdx.y;
  const int wm = wave >> 1, wn = wave & 1;

  const int arow0 = tid >> 3;
  const int ak8s  = (tid & 7) ^ (arow0 & 7);
  const f16* aptr = h + (size_t)(bm * 256 + arow0) * INTER + ak8s * 8;
  const int aoff = tid * 16;

  const int brow0 = tid >> 3;
  const uint32_t* qp = dq_ + (size_t)(bn * 128 + brow0) * (INTER / 2) + (tid & 7) * 4;
  const float* sp = dsc + (size_t)(bn * 128 + brow0) * NG2;
  const float* zp = dz + (size_t)(bn * 128 + brow0) * NG2;
  const int bws0 = brow0 * 128 + (((tid & 7) ^ (brow0 & 7)) << 4);

  int abase[4], asel[4];
#pragma unroll
  for (int im = 0; im < 4; ++im) {
    int r = wm * 64 + im * 16 + (lane & 15);
    abase[im] = r * 128; asel[im] = r & 7;
  }
  int bbase[4], bsel[4];
#pragma unroll
  for (int in_ = 0; in_ < 4; ++in_) {
    int r = wn * 64 + in_ * 16 + (lane & 15);
    bbase[in_] = r * 128; bsel[in_] = r & 7;
  }
  const int kchunk = lane >> 4;

  f32x4 acc[4][4] = {};

  auto stageA = [&](const f16* src, f16* dst) {
#pragma unroll
    for (int i = 0; i < 4; ++i)
      g2lds16(src + (size_t)i * 64 * INTER, (char*)dst + aoff + i * 8192);
  };
  auto loadB = [&](int ktn, uint4& w0, uint4& w1,
                   float& s0f, float& z0f, float& s1f, float& z1f) {
    w0 = *(const uint4*)(qp + (size_t)ktn * 32);
    w1 = *(const uint4*)(qp + (size_t)64 * (INTER / 2) + (size_t)ktn * 32);
    s0f = sp[ktn]; z0f = zp[ktn];
    s1f = sp[64 * NG2 + ktn]; z1f = zp[64 * NG2 + ktn];
  };
  auto writeB = [&](uint4 w0, uint4 w1, float s0f, float z0f, float s1f, float z1f) {
    __half2 s0 = __float2half2_rn(s0f), n0 = __float2half2_rn(-z0f * s0f);
    __half2 s1 = __float2half2_rn(s1f), n1 = __float2half2_rn(-z1f * s1f);
    uint4 o0, o1;
    o0.x = dq2(w0.x, s0, n0); o0.y = dq2(w0.y, s0, n0);
    o0.z = dq2(w0.z, s0, n0); o0.w = dq2(w0.w, s0, n0);
    o1.x = dq2(w1.x, s1, n1); o1.y = dq2(w1.y, s1, n1);
    o1.z = dq2(w1.z, s1, n1); o1.w = dq2(w1.w, s1, n1);
    *(uint4*)(lB + bws0) = o0;
    *(uint4*)(lB + bws0 + 64 * 128) = o1;
  };
  auto compute = [&](const f16* lA) {
#pragma unroll
    for (int ks = 0; ks < 2; ++ks) {
      int kc = ks * 4 + kchunk;
      f16x8 a[4], b[4];
#pragma unroll
      for (int im = 0; im < 4; ++im)
        a[im] = *(const f16x8*)((const char*)lA + abase[im] + ((kc ^ asel[im]) << 4));
#pragma unroll
      for (int in_ = 0; in_ < 4; ++in_)
        b[in_] = *(const f16x8*)(lB + bbase[in_] + ((kc ^ bsel[in_]) << 4));
#pragma unroll
      for (int im = 0; im < 4; ++im)
#pragma unroll
        for (int in_ = 0; in_ < 4; ++in_)
          acc[im][in_] = __builtin_amdgcn_mfma_f32_16x16x32_f16(a[im], b[in_], acc[im][in_], 0, 0, 0);
    }
  };

  stageA(aptr, lA0);
  {
    uint4 w0, w1; float s0f, z0f, s1f, z1f;
    loadB(0, w0, w1, s0f, z0f, s1f, z1f);
    writeB(w0, w1, s0f, z0f, s1f, z1f);
  }
  __syncthreads();

  for (int kt = 0; kt < NG2 - 1; ++kt) {
    stageA(aptr + (size_t)(kt + 1) * 64, (kt & 1) ? lA0 : lA1);
    uint4 w0, w1; float s0f, z0f, s1f, z1f;
    loadB(kt + 1, w0, w1, s0f, z0f, s1f, z1f);
    compute((kt & 1) ? lA1 : lA0);
    __syncthreads();
    writeB(w0, w1, s0f, z0f, s1f, z1f);
    __syncthreads();
  }
  compute(((NG2 - 1) & 1) ? lA1 : lA0);

#pragma unroll
  for (int im = 0; im < 4; ++im)
#pragma unroll
    for (int in_ = 0; in_ < 4; ++in_)
#pragma unroll
      for (int r = 0; r < 4; ++r) {
        int row = bm * 256 + wm * 64 + im * 16 + (lane >> 4) * 4 + r;
        int col = bn * 128 + wn * 64 + in_ * 16 + (lane & 15);
        out[(size_t)row * HIDDEN + col] = acc[im][in_][r];
      }
}

// ------------------------------------------------------------------- launcher
extern "C" void kernel_launch(void* const* d_in, const int* in_sizes, int n_in,
                              void* d_out, int out_size, void* d_ws, size_t ws_size,
                              hipStream_t stream) {
  const float*    x   = (const float*)d_in[0];
  const uint32_t* gq  = (const uint32_t*)d_in[1];
  const uint32_t* uq  = (const uint32_t*)d_in[2];
  const uint32_t* dqw = (const uint32_t*)d_in[3];
  const float*    gs  = (const float*)d_in[4];
  const float*    gz  = (const float*)d_in[5];
  const float*    us  = (const float*)d_in[6];
  const float*    uz  = (const float*)d_in[7];
  const float*    dsc = (const float*)d_in[8];
  const float*    dzz = (const float*)d_in[9];

  const size_t XH = (size_t)NTOK * HIDDEN * 2;          // 33.6 MB
  const size_t HB = (size_t)NTOK * INTER * 2;           // 90.2 MB
  const size_t WB = (size_t)INTER * HIDDEN * 2;         // 90.2 MB
  f16* xh   = (f16*)d_ws;
  f16* hbuf = (f16*)((char*)d_ws + XH);
  float* out = (float*)d_out;

  const int LDS_BYTES = 80 * 1024;

  cvt_x<<<dim3((NTOK * HIDDEN) / (256 * 8)), 256, 0, stream>>>(x, xh);

  if (ws_size >= XH + HB + 2 * WB) {
    // fast path: dequant each weight once, f16-B GEMMs (round-0 skeleton)
    f16* W1 = (f16*)((char*)d_ws + XH + HB);            // gate, later down
    f16* W2 = (f16*)((char*)d_ws + XH + HB + WB);       // up
    (void)hipFuncSetAttribute((const void*)gemm_gateup_f,
                              hipFuncAttributeMaxDynamicSharedMemorySize, LDS_BYTES);
    (void)hipFuncSetAttribute((const void*)gemm_down_f,
                              hipFuncAttributeMaxDynamicSharedMemorySize, LDS_BYTES);
    deq_w<<<dim3((INTER * NG1) / 256), 256, 0, stream>>>(gq, gs, gz, W1);
    deq_w<<<dim3((INTER * NG1) / 256), 256, 0, stream>>>(uq, us, uz, W2);
    gemm_gateup_f<<<dim3(NTOK / 256, INTER / 64), 512, LDS_BYTES, stream>>>(
        xh, W1, W2, hbuf);
    deq_w<<<dim3((HIDDEN * NG2) / 256), 256, 0, stream>>>(dqw, dsc, dzz, W1);
    gemm_down_f<<<dim3(NTOK / 256, HIDDEN / 128), 512, LDS_BYTES, stream>>>(
        hbuf, W1, out);
  } else {
    // fallback: round-0 proven kernels (dequant in-GEMM)
    (void)hipFuncSetAttribute((const void*)gemm_gateup_q,
                              hipFuncAttributeMaxDynamicSharedMemorySize, LDS_BYTES);
    (void)hipFuncSetAttribute((const void*)gemm_down_q,
                              hipFuncAttributeMaxDynamicSharedMemorySize, LDS_BYTES);
    gemm_gateup_q<<<dim3(NTOK / 256, INTER / 64), 512, LDS_BYTES, stream>>>(
        xh, gq, uq, gs, gz, us, uz, hbuf);
    gemm_down_q<<<dim3(NTOK / 256, HIDDEN / 128), 512, LDS_BYTES, stream>>>(
        hbuf, dqw, dsc, dzz, out);
  }
}